// Round 20
// baseline (894.228 us; speedup 1.0000x reference)
//
#include <hip/hip_runtime.h>
#include <hip/hip_fp16.h>

// LSTM T=512 B=64 D=256 H=256, fp32 in/out.
//
// Phase 0: X->f16; Wxt [4H][K] f16; Wh8 = Wh*64 quantized to fp8 e4m3,
//          MFMA B-fragment order, unit-major columns (c=4u+g).
// Phase 1: gx = X @ Wx + b via f16 MFMA GEMM -> ws f16 (unit-major store).
// Phase 2: recurrence, 1 CU/batch, 1024 thr (16 waves, 4/SIMD).
//          R17-R19 verdict: accvgpr-move tax is not removable at HIP level
//          (asm MFMA corrupts acc; "+v" pins add copies). So: accept the
//          moves, HIDE the latency with 4-way TLP. Wave owns 4 N-tiles
//          (32 B-longs + 8 A-longs + 4 accs ~ 116 regs < 128 unified budget
//          at 4 waves/SIMD). Full Wh8 still register-resident per CU.
//          Per-wave epilogue lanes 0..15 (units [16w,16w+16), same-wave act
//          behind lgkmcnt fence); ONE barrier/step (hbuf double buffer).

#define T_STEPS 512
#define BATCH   64
#define HID     256
#define G4      1024
#define GM      (T_STEPS * BATCH)     // 32768

typedef _Float16 half2_t __attribute__((ext_vector_type(2)));
typedef _Float16 f16x8   __attribute__((ext_vector_type(8)));
typedef float    f32x4   __attribute__((ext_vector_type(4)));

// ws layout
#define XH_OFF  0u          // f16[32768][256]
#define WXT_OFF 8388608u    // f16[1024][256]
#define GX_OFF  8912896u    // f16[32768][1024]
#define WH8_BYTE_OFF (8650752u * 2u)   // 256 KB fp8 frag-packed Wh

__device__ __forceinline__ float fast_sigmoid(float x) {
    return 1.0f / (1.0f + __expf(-x));
}
__device__ __forceinline__ float fast_tanh(float x) {
    return 2.0f / (1.0f + __expf(-2.0f * x)) - 1.0f;
}

// ---- fp8 e4m3fn encode (RN; flush |x|<2^-6 to 0; clamp to 448) ----
__device__ __forceinline__ unsigned char sw_e4m3(float x) {
    unsigned u = __float_as_uint(x);
    unsigned s = (u >> 24) & 0x80u;
    int e = (int)((u >> 23) & 0xffu) - 127;
    unsigned m = u & 0x7fffffu;
    if (e < -6) return (unsigned char)s;
    m += 0x00080000u;
    if (m & 0x800000u) { m = 0; e += 1; }
    int E = e + 7;
    if (E > 15 || (E == 15 && (m >> 20) > 6)) { E = 15; m = 6u << 20; }
    return (unsigned char)(s | ((unsigned)E << 3) | (m >> 20));
}
template <bool HI>
__device__ __forceinline__ unsigned cvt2_fp8(float a, float b, unsigned old) {
#if __has_builtin(__builtin_amdgcn_cvt_pk_fp8_f32)
    return (unsigned)__builtin_amdgcn_cvt_pk_fp8_f32(a, b, (int)old, HI);
#else
    unsigned lo16 = (unsigned)sw_e4m3(a) | ((unsigned)sw_e4m3(b) << 8);
    return HI ? ((old & 0xFFFFu) | (lo16 << 16))
              : ((old & 0xFFFF0000u) | lo16);
#endif
}

// ---------------- Phase 0a: X f32 -> f16 ----------------
__global__ __launch_bounds__(256) void k_prep_x(const float* __restrict__ X,
                                                _Float16* __restrict__ Xh) {
    const int i = blockIdx.x * 256 + threadIdx.x;
    float4 v = ((const float4*)X)[i];
    half2_t a; a.x = (_Float16)v.x; a.y = (_Float16)v.y;
    half2_t b; b.x = (_Float16)v.z; b.y = (_Float16)v.w;
    ((half2_t*)Xh)[2 * i]     = a;
    ((half2_t*)Xh)[2 * i + 1] = b;
}

// ---------------- Phase 0b: Wxt [4H][K] (gate-major cols) ----------------
__global__ __launch_bounds__(256) void k_prep_w(
    const float* __restrict__ Wax, const float* __restrict__ Wix,
    const float* __restrict__ Wfx, const float* __restrict__ Wox,
    _Float16* __restrict__ Wxt)
{
    const int id = blockIdx.x * 256 + threadIdx.x;
    const int k  = id >> 10;
    const int c  = id & 1023;
    const int g  = c >> 8;
    const int j  = c & 255;
    const float* src = (g == 0) ? Wax : (g == 1) ? Wix : (g == 2) ? Wfx : Wox;
    Wxt[c * 256 + k] = (_Float16)src[k * 256 + j];
}

// ---------------- Phase 0c: Wh8 fp8 fragments, unit-major cols -----------
__global__ __launch_bounds__(256) void k_prep_wfrag8(
    const float* __restrict__ Wah, const float* __restrict__ Wih,
    const float* __restrict__ Wfh, const float* __restrict__ Woh,
    unsigned char* __restrict__ Wh8)
{
    const int id  = blockIdx.x * 256 + threadIdx.x;   // [0, 32768)
    const int l   = id & 63;
    const int kt  = (id >> 6) & 7;
    const int ntG = id >> 9;
    const int c   = ntG * 16 + (l & 15);
    const int u   = c >> 2;
    const int g   = c & 3;
    const int k0  = kt * 32 + (l >> 4) * 8;
    const float* W = (g == 0) ? Wah : (g == 1) ? Wih : (g == 2) ? Wfh : Woh;
    float v[8];
#pragma unroll
    for (int e = 0; e < 8; ++e)
        v[e] = W[(size_t)(k0 + e) * 256 + u] * 64.0f;
    unsigned lo = cvt2_fp8<false>(v[0], v[1], 0u);
    lo = cvt2_fp8<true>(v[2], v[3], lo);
    unsigned hi = cvt2_fp8<false>(v[4], v[5], 0u);
    hi = cvt2_fp8<true>(v[6], v[7], hi);
    uint2 pk; pk.x = lo; pk.y = hi;
    *(uint2*)(Wh8 + ((size_t)(ntG * 8 + kt) * 64 + l) * 8) = pk;
}

// ---------------- Phase 1: gx = Xh @ Wxt^T + b (unit-major store) --------
__global__ __launch_bounds__(256) void k_gemm(const _Float16* __restrict__ Xh,
                                              const _Float16* __restrict__ Wxt,
                                              const float* __restrict__ ba,
                                              const float* __restrict__ bi,
                                              const float* __restrict__ bf_,
                                              const float* __restrict__ bo,
                                              _Float16* __restrict__ gx)
{
    const int lane = threadIdx.x & 63, wave = threadIdx.x >> 6;
    const int rowbase = blockIdx.x * 128 + wave * 32;
    const int colbase = blockIdx.y * 64;
    const int r15 = lane & 15, kg = lane >> 4;

    f32x4 acc[2][4] = {};
    const _Float16* ap0 = Xh  + (size_t)(rowbase + r15) * 256 + kg * 8;
    const _Float16* ap1 = ap0 + 16 * 256;
    const _Float16* bp  = Wxt + (size_t)(colbase + r15) * 256 + kg * 8;

#pragma unroll
    for (int ks = 0; ks < 8; ++ks) {
        f16x8 a0 = *(const f16x8*)(ap0 + ks * 32);
        f16x8 a1 = *(const f16x8*)(ap1 + ks * 32);
        f16x8 b0 = *(const f16x8*)(bp  + ks * 32);
        f16x8 b1 = *(const f16x8*)(bp  + 16 * 256 + ks * 32);
        f16x8 b2 = *(const f16x8*)(bp  + 32 * 256 + ks * 32);
        f16x8 b3 = *(const f16x8*)(bp  + 48 * 256 + ks * 32);
        acc[0][0] = __builtin_amdgcn_mfma_f32_16x16x32_f16(a0, b0, acc[0][0], 0, 0, 0);
        acc[0][1] = __builtin_amdgcn_mfma_f32_16x16x32_f16(a0, b1, acc[0][1], 0, 0, 0);
        acc[0][2] = __builtin_amdgcn_mfma_f32_16x16x32_f16(a0, b2, acc[0][2], 0, 0, 0);
        acc[0][3] = __builtin_amdgcn_mfma_f32_16x16x32_f16(a0, b3, acc[0][3], 0, 0, 0);
        acc[1][0] = __builtin_amdgcn_mfma_f32_16x16x32_f16(a1, b0, acc[1][0], 0, 0, 0);
        acc[1][1] = __builtin_amdgcn_mfma_f32_16x16x32_f16(a1, b1, acc[1][1], 0, 0, 0);
        acc[1][2] = __builtin_amdgcn_mfma_f32_16x16x32_f16(a1, b2, acc[1][2], 0, 0, 0);
        acc[1][3] = __builtin_amdgcn_mfma_f32_16x16x32_f16(a1, b3, acc[1][3], 0, 0, 0);
    }
    float bias_n[4];
#pragma unroll
    for (int nt = 0; nt < 4; ++nt) {
        int col = colbase + nt * 16 + r15;
        bias_n[nt] = (col < 256) ? ba[col]
                   : (col < 512) ? bi[col - 256]
                   : (col < 768) ? bf_[col - 512]
                                 : bo[col - 768];
    }
    // unit-major permuted store: col (= g*256+j) -> 4*j + g
#pragma unroll
    for (int mt = 0; mt < 2; ++mt)
#pragma unroll
        for (int nt = 0; nt < 4; ++nt)
#pragma unroll
            for (int r = 0; r < 4; ++r) {
                int row = rowbase + mt * 16 + kg * 4 + r;
                int col = colbase + nt * 16 + r15;
                int g   = col >> 8, j = col & 255;
                gx[(size_t)row * G4 + 4 * j + g] =
                    (_Float16)(acc[mt][nt][r] + bias_n[nt]);
            }
}

// ---------------- Phase 2: fp8 MFMA recurrence (16 waves, 4/SIMD) --------

#define M8(a, bfr, acc) \
    __builtin_amdgcn_mfma_f32_16x16x32_fp8_fp8((a), (bfr), (acc), 0, 0, 0)
#define WB(n, k) (*(const long*)(Wp + ((size_t)((n) * 8 + (k)) * 64) * 8))

#define DB(n)                                                                  \
    long b##n##_0 = WB(n,0), b##n##_1 = WB(n,1), b##n##_2 = WB(n,2),           \
         b##n##_3 = WB(n,3), b##n##_4 = WB(n,4), b##n##_5 = WB(n,5),           \
         b##n##_6 = WB(n,6), b##n##_7 = WB(n,7);

// 4 independent MFMAs per k-step (one per owned tile)
#define KSTEP(k)                                                               \
    c0 = M8(a##k, b0_##k, c0);  c1 = M8(a##k, b1_##k, c1);                     \
    c2 = M8(a##k, b2_##k, c2);  c3 = M8(a##k, b3_##k, c3);

__global__ void __launch_bounds__(1024, 1)
__attribute__((amdgpu_waves_per_eu(4, 4)))
k_recur(const unsigned char* __restrict__ Wh8, const _Float16* __restrict__ gx,
        float* __restrict__ out)
{
    const int b    = blockIdx.x;
    const int tid  = threadIdx.x;      // 0..1023
    const int lane = tid & 63;
    const int w    = tid >> 6;         // wave 0..15: tiles [4w,4w+4), units [16w,+16)

    __shared__ __align__(16) float act[1024];          // 4 KB
    __shared__ __align__(8)  unsigned char hbufs[2][256];

    const unsigned char* Wp = Wh8 + ((size_t)(w * 4) * 8 * 64) * 8 + lane * 8;

    // ---- 32 B-fragment longs per wave (full Wh8 resident across 16 waves) ----
    DB(0) DB(1) DB(2) DB(3)

    if (tid < 256) hbufs[0][tid] = 0;  // h0 = 0
    float s = 0.0f;
    const int u = w * 16 + lane;       // epilogue unit (valid for lane < 16)
    uint2 gcu; gcu.x = 0u; gcu.y = 0u;
    if (lane < 16)
        gcu = *(const uint2*)(gx + (size_t)b * G4 + 4 * u);  // a,i,f,o packed
    __syncthreads();

#pragma unroll 1
    for (int t = 0; t < T_STEPS; ++t) {
        // prefetch next-step gx: ONE 8B load (unit-major layout)
        uint2 gnx; gnx.x = 0u; gnx.y = 0u;
        if (lane < 16 && t + 1 < T_STEPS) {
            gnx = *(const uint2*)(gx + ((size_t)(t + 1) * BATCH + b) * G4 + 4 * u);
        }

        // ---- A-fragments: fp8 h broadcast ----
        const unsigned char* hb = &hbufs[t & 1][0] + ((lane >> 4) * 8);
        long a0 = *(const long*)(hb + 0);
        long a1 = *(const long*)(hb + 32);
        long a2 = *(const long*)(hb + 64);
        long a3 = *(const long*)(hb + 96);
        long a4 = *(const long*)(hb + 128);
        long a5 = *(const long*)(hb + 160);
        long a6 = *(const long*)(hb + 192);
        long a7 = *(const long*)(hb + 224);

        f32x4 c0 = {0,0,0,0}, c1 = {0,0,0,0}, c2 = {0,0,0,0}, c3 = {0,0,0,0};

        KSTEP(0) KSTEP(1) KSTEP(2) KSTEP(3)
        KSTEP(4) KSTEP(5) KSTEP(6) KSTEP(7)

        // store row 0 of each owned C tile (lanes 0..15); global tile = 4w+n
        if (lane < 16) {
            act[(w * 4 + 0) * 16 + lane] = c0[0];
            act[(w * 4 + 1) * 16 + lane] = c1[0];
            act[(w * 4 + 2) * 16 + lane] = c2[0];
            act[(w * 4 + 3) * 16 + lane] = c3[0];
        }
        asm volatile("s_waitcnt lgkmcnt(0)" ::: "memory");  // same-wave act done

        // ---- per-wave epilogue: lanes 0..15, unit u = 16w + lane ----
        if (lane < 16) {
            half2_t p01, p23;
            __builtin_memcpy(&p01, &gcu.x, 4);
            __builtin_memcpy(&p23, &gcu.y, 4);
            float4 g4v = ((const float4*)act)[u];              // a,i,f,o raw
            const float S = 0.0009765625f;                     // 2^-10
            float gA = g4v.x * S + (float)p01.x;
            float gB = g4v.y * S + (float)p01.y;
            float gC = g4v.z * S + (float)p23.x;
            float gD = g4v.w * S + (float)p23.y;
            float aa = fast_tanh(gA);
            float ii = fast_sigmoid(gB);
            float ff = fast_sigmoid(gC);
            float oo = fast_sigmoid(gD);
            s = aa * ii + s * ff;
            float h = fast_tanh(s) * oo;
            out[((size_t)t * BATCH + b) * HID + u] = h;
            unsigned p8 = cvt2_fp8<false>(h * 16.0f, h * 16.0f, 0u);
            hbufs[(t + 1) & 1][u] = (unsigned char)(p8 & 0xffu);
        }
        gcu = gnx;
        __syncthreads();   // hbuf slot complete before t+1 A-reads (1/step)
    }
}

extern "C" void kernel_launch(void* const* d_in, const int* in_sizes, int n_in,
                              void* d_out, int out_size, void* d_ws, size_t ws_size,
                              hipStream_t stream) {
    const float* X   = (const float*)d_in[0];
    const float* Wax = (const float*)d_in[1];
    const float* Wix = (const float*)d_in[2];
    const float* Wfx = (const float*)d_in[3];
    const float* Wox = (const float*)d_in[4];
    const float* Wah = (const float*)d_in[5];
    const float* Wih = (const float*)d_in[6];
    const float* Wfh = (const float*)d_in[7];
    const float* Woh = (const float*)d_in[8];
    const float* ba  = (const float*)d_in[9];
    const float* bi  = (const float*)d_in[10];
    const float* bf  = (const float*)d_in[11];
    const float* bo  = (const float*)d_in[12];

    _Float16* ws  = (_Float16*)d_ws;
    _Float16* Xh  = ws + XH_OFF;
    _Float16* Wxt = ws + WXT_OFF;
    _Float16* gxp = ws + GX_OFF;
    unsigned char* Wh8 = (unsigned char*)d_ws + WH8_BYTE_OFF;

    k_prep_x<<<dim3(GM * 256 / 4 / 256), dim3(256), 0, stream>>>(X, Xh);
    k_prep_w<<<dim3(1024), dim3(256), 0, stream>>>(Wax, Wix, Wfx, Wox, Wxt);
    k_prep_wfrag8<<<dim3(128), dim3(256), 0, stream>>>(Wah, Wih, Wfh, Woh, Wh8);
    k_gemm<<<dim3(GM / 128, G4 / 64), dim3(256), 0, stream>>>(
        Xh, Wxt, ba, bi, bf, bo, gxp);
    k_recur<<<dim3(BATCH), dim3(1024), 0, stream>>>(Wh8, gxp, (float*)d_out);
}

// Round 21
// 848.687 us; speedup vs baseline: 1.0537x; 1.0537x over previous
//
#include <hip/hip_runtime.h>
#include <hip/hip_fp16.h>

// LSTM T=512 B=64 D=256 H=256, fp32 in/out.
//
// Phase 0: X->f16; Wxt [4H][K] f16; Wh8 = Wh*64 quantized to fp8 e4m3,
//          MFMA B-fragment order, unit-major columns (c=4u+g).
// Phase 1: gx = X @ Wx + b via f16 MFMA GEMM -> ws f16 (unit-major store).
// Phase 2: recurrence, 1 CU/batch, 512 thr (8 waves, 2/SIMD) = R16 config
//          (fastest: 733us; 2-wave TLP, 8 N-tiles/wave register-resident fp8)
//          + R17's per-wave epilogue WITHOUT the broken asm-MFMA:
//          wave w owns tiles [8w,8w+8) = units [32w,32w+32); lanes 0..31
//          update them reading ONLY own-wave act region behind an lgkmcnt
//          fence -> ONE barrier/step (hbuf double-buffer publish).
//          accvgpr-move tax accepted (R17-R19: not removable at HIP level).

#define T_STEPS 512
#define BATCH   64
#define HID     256
#define G4      1024
#define GM      (T_STEPS * BATCH)     // 32768

typedef _Float16 half2_t __attribute__((ext_vector_type(2)));
typedef _Float16 f16x8   __attribute__((ext_vector_type(8)));
typedef float    f32x4   __attribute__((ext_vector_type(4)));

// ws layout
#define XH_OFF  0u          // f16[32768][256]
#define WXT_OFF 8388608u    // f16[1024][256]
#define GX_OFF  8912896u    // f16[32768][1024]
#define WH8_BYTE_OFF (8650752u * 2u)   // 256 KB fp8 frag-packed Wh

__device__ __forceinline__ float fast_sigmoid(float x) {
    return 1.0f / (1.0f + __expf(-x));
}
__device__ __forceinline__ float fast_tanh(float x) {
    return 2.0f / (1.0f + __expf(-2.0f * x)) - 1.0f;
}

// ---- fp8 e4m3fn encode (RN; flush |x|<2^-6 to 0; clamp to 448) ----
__device__ __forceinline__ unsigned char sw_e4m3(float x) {
    unsigned u = __float_as_uint(x);
    unsigned s = (u >> 24) & 0x80u;
    int e = (int)((u >> 23) & 0xffu) - 127;
    unsigned m = u & 0x7fffffu;
    if (e < -6) return (unsigned char)s;
    m += 0x00080000u;
    if (m & 0x800000u) { m = 0; e += 1; }
    int E = e + 7;
    if (E > 15 || (E == 15 && (m >> 20) > 6)) { E = 15; m = 6u << 20; }
    return (unsigned char)(s | ((unsigned)E << 3) | (m >> 20));
}
template <bool HI>
__device__ __forceinline__ unsigned cvt2_fp8(float a, float b, unsigned old) {
#if __has_builtin(__builtin_amdgcn_cvt_pk_fp8_f32)
    return (unsigned)__builtin_amdgcn_cvt_pk_fp8_f32(a, b, (int)old, HI);
#else
    unsigned lo16 = (unsigned)sw_e4m3(a) | ((unsigned)sw_e4m3(b) << 8);
    return HI ? ((old & 0xFFFFu) | (lo16 << 16))
              : ((old & 0xFFFF0000u) | lo16);
#endif
}

// ---------------- Phase 0a: X f32 -> f16 ----------------
__global__ __launch_bounds__(256) void k_prep_x(const float* __restrict__ X,
                                                _Float16* __restrict__ Xh) {
    const int i = blockIdx.x * 256 + threadIdx.x;
    float4 v = ((const float4*)X)[i];
    half2_t a; a.x = (_Float16)v.x; a.y = (_Float16)v.y;
    half2_t b; b.x = (_Float16)v.z; b.y = (_Float16)v.w;
    ((half2_t*)Xh)[2 * i]     = a;
    ((half2_t*)Xh)[2 * i + 1] = b;
}

// ---------------- Phase 0b: Wxt [4H][K] (gate-major cols) ----------------
__global__ __launch_bounds__(256) void k_prep_w(
    const float* __restrict__ Wax, const float* __restrict__ Wix,
    const float* __restrict__ Wfx, const float* __restrict__ Wox,
    _Float16* __restrict__ Wxt)
{
    const int id = blockIdx.x * 256 + threadIdx.x;
    const int k  = id >> 10;
    const int c  = id & 1023;
    const int g  = c >> 8;
    const int j  = c & 255;
    const float* src = (g == 0) ? Wax : (g == 1) ? Wix : (g == 2) ? Wfx : Wox;
    Wxt[c * 256 + k] = (_Float16)src[k * 256 + j];
}

// ---------------- Phase 0c: Wh8 fp8 fragments, unit-major cols -----------
__global__ __launch_bounds__(256) void k_prep_wfrag8(
    const float* __restrict__ Wah, const float* __restrict__ Wih,
    const float* __restrict__ Wfh, const float* __restrict__ Woh,
    unsigned char* __restrict__ Wh8)
{
    const int id  = blockIdx.x * 256 + threadIdx.x;   // [0, 32768)
    const int l   = id & 63;
    const int kt  = (id >> 6) & 7;
    const int ntG = id >> 9;
    const int c   = ntG * 16 + (l & 15);
    const int u   = c >> 2;
    const int g   = c & 3;
    const int k0  = kt * 32 + (l >> 4) * 8;
    const float* W = (g == 0) ? Wah : (g == 1) ? Wih : (g == 2) ? Wfh : Woh;
    float v[8];
#pragma unroll
    for (int e = 0; e < 8; ++e)
        v[e] = W[(size_t)(k0 + e) * 256 + u] * 64.0f;
    unsigned lo = cvt2_fp8<false>(v[0], v[1], 0u);
    lo = cvt2_fp8<true>(v[2], v[3], lo);
    unsigned hi = cvt2_fp8<false>(v[4], v[5], 0u);
    hi = cvt2_fp8<true>(v[6], v[7], hi);
    uint2 pk; pk.x = lo; pk.y = hi;
    *(uint2*)(Wh8 + ((size_t)(ntG * 8 + kt) * 64 + l) * 8) = pk;
}

// ---------------- Phase 1: gx = Xh @ Wxt^T + b (unit-major store) --------
__global__ __launch_bounds__(256) void k_gemm(const _Float16* __restrict__ Xh,
                                              const _Float16* __restrict__ Wxt,
                                              const float* __restrict__ ba,
                                              const float* __restrict__ bi,
                                              const float* __restrict__ bf_,
                                              const float* __restrict__ bo,
                                              _Float16* __restrict__ gx)
{
    const int lane = threadIdx.x & 63, wave = threadIdx.x >> 6;
    const int rowbase = blockIdx.x * 128 + wave * 32;
    const int colbase = blockIdx.y * 64;
    const int r15 = lane & 15, kg = lane >> 4;

    f32x4 acc[2][4] = {};
    const _Float16* ap0 = Xh  + (size_t)(rowbase + r15) * 256 + kg * 8;
    const _Float16* ap1 = ap0 + 16 * 256;
    const _Float16* bp  = Wxt + (size_t)(colbase + r15) * 256 + kg * 8;

#pragma unroll
    for (int ks = 0; ks < 8; ++ks) {
        f16x8 a0 = *(const f16x8*)(ap0 + ks * 32);
        f16x8 a1 = *(const f16x8*)(ap1 + ks * 32);
        f16x8 b0 = *(const f16x8*)(bp  + ks * 32);
        f16x8 b1 = *(const f16x8*)(bp  + 16 * 256 + ks * 32);
        f16x8 b2 = *(const f16x8*)(bp  + 32 * 256 + ks * 32);
        f16x8 b3 = *(const f16x8*)(bp  + 48 * 256 + ks * 32);
        acc[0][0] = __builtin_amdgcn_mfma_f32_16x16x32_f16(a0, b0, acc[0][0], 0, 0, 0);
        acc[0][1] = __builtin_amdgcn_mfma_f32_16x16x32_f16(a0, b1, acc[0][1], 0, 0, 0);
        acc[0][2] = __builtin_amdgcn_mfma_f32_16x16x32_f16(a0, b2, acc[0][2], 0, 0, 0);
        acc[0][3] = __builtin_amdgcn_mfma_f32_16x16x32_f16(a0, b3, acc[0][3], 0, 0, 0);
        acc[1][0] = __builtin_amdgcn_mfma_f32_16x16x32_f16(a1, b0, acc[1][0], 0, 0, 0);
        acc[1][1] = __builtin_amdgcn_mfma_f32_16x16x32_f16(a1, b1, acc[1][1], 0, 0, 0);
        acc[1][2] = __builtin_amdgcn_mfma_f32_16x16x32_f16(a1, b2, acc[1][2], 0, 0, 0);
        acc[1][3] = __builtin_amdgcn_mfma_f32_16x16x32_f16(a1, b3, acc[1][3], 0, 0, 0);
    }
    float bias_n[4];
#pragma unroll
    for (int nt = 0; nt < 4; ++nt) {
        int col = colbase + nt * 16 + r15;
        bias_n[nt] = (col < 256) ? ba[col]
                   : (col < 512) ? bi[col - 256]
                   : (col < 768) ? bf_[col - 512]
                                 : bo[col - 768];
    }
    // unit-major permuted store: col (= g*256+j) -> 4*j + g
#pragma unroll
    for (int mt = 0; mt < 2; ++mt)
#pragma unroll
        for (int nt = 0; nt < 4; ++nt)
#pragma unroll
            for (int r = 0; r < 4; ++r) {
                int row = rowbase + mt * 16 + kg * 4 + r;
                int col = colbase + nt * 16 + r15;
                int g   = col >> 8, j = col & 255;
                gx[(size_t)row * G4 + 4 * j + g] =
                    (_Float16)(acc[mt][nt][r] + bias_n[nt]);
            }
}

// ---------------- Phase 2: fp8 MFMA recurrence (8 waves, per-wave epi) ---

#define M8(a, bfr, acc) \
    __builtin_amdgcn_mfma_f32_16x16x32_fp8_fp8((a), (bfr), (acc), 0, 0, 0)
#define WB(n, k) (*(const long*)(Wp + ((size_t)((n) * 8 + (k)) * 64) * 8))

#define DB(n)                                                                  \
    long b##n##_0 = WB(n,0), b##n##_1 = WB(n,1), b##n##_2 = WB(n,2),           \
         b##n##_3 = WB(n,3), b##n##_4 = WB(n,4), b##n##_5 = WB(n,5),           \
         b##n##_6 = WB(n,6), b##n##_7 = WB(n,7);

// 8 independent MFMAs per k-step (one per owned tile)
#define KSTEP(k)                                                               \
    c0 = M8(a##k, b0_##k, c0);  c1 = M8(a##k, b1_##k, c1);                     \
    c2 = M8(a##k, b2_##k, c2);  c3 = M8(a##k, b3_##k, c3);                     \
    c4 = M8(a##k, b4_##k, c4);  c5 = M8(a##k, b5_##k, c5);                     \
    c6 = M8(a##k, b6_##k, c6);  c7 = M8(a##k, b7_##k, c7);

__global__ void __launch_bounds__(512, 1)
__attribute__((amdgpu_waves_per_eu(2, 2)))
k_recur(const unsigned char* __restrict__ Wh8, const _Float16* __restrict__ gx,
        float* __restrict__ out)
{
    const int b    = blockIdx.x;
    const int tid  = threadIdx.x;      // 0..511
    const int lane = tid & 63;
    const int w    = tid >> 6;         // wave 0..7: tiles [8w,8w+8), units [32w,+32)

    __shared__ __align__(16) float act[1024];          // 4 KB
    __shared__ __align__(8)  unsigned char hbufs[2][256];

    const unsigned char* Wp = Wh8 + ((size_t)(w * 8) * 8 * 64) * 8 + lane * 8;

    // ---- 64 register-resident fp8 B-fragment longs ----
    DB(0) DB(1) DB(2) DB(3) DB(4) DB(5) DB(6) DB(7)

    if (tid < 256) hbufs[0][tid] = 0;  // h0 = 0
    float s = 0.0f;
    const int u = w * 32 + lane;       // epilogue unit (valid for lane < 32)
    uint2 gcu; gcu.x = 0u; gcu.y = 0u;
    if (lane < 32)
        gcu = *(const uint2*)(gx + (size_t)b * G4 + 4 * u);  // a,i,f,o packed
    __syncthreads();

#pragma unroll 1
    for (int t = 0; t < T_STEPS; ++t) {
        // prefetch next-step gx: ONE 8B load (unit-major layout)
        uint2 gnx; gnx.x = 0u; gnx.y = 0u;
        if (lane < 32 && t + 1 < T_STEPS) {
            gnx = *(const uint2*)(gx + ((size_t)(t + 1) * BATCH + b) * G4 + 4 * u);
        }

        // ---- A-fragments: fp8 h broadcast ----
        const unsigned char* hb = &hbufs[t & 1][0] + ((lane >> 4) * 8);
        long a0 = *(const long*)(hb + 0);
        long a1 = *(const long*)(hb + 32);
        long a2 = *(const long*)(hb + 64);
        long a3 = *(const long*)(hb + 96);
        long a4 = *(const long*)(hb + 128);
        long a5 = *(const long*)(hb + 160);
        long a6 = *(const long*)(hb + 192);
        long a7 = *(const long*)(hb + 224);

        f32x4 c0 = {0,0,0,0}, c1 = {0,0,0,0}, c2 = {0,0,0,0}, c3 = {0,0,0,0};
        f32x4 c4 = {0,0,0,0}, c5 = {0,0,0,0}, c6 = {0,0,0,0}, c7 = {0,0,0,0};

        KSTEP(0) KSTEP(1) KSTEP(2) KSTEP(3)
        KSTEP(4) KSTEP(5) KSTEP(6) KSTEP(7)

        // store row 0 of each owned C tile (lanes 0..15); global tile = 8w+n
        if (lane < 16) {
            act[(w * 8 + 0) * 16 + lane] = c0[0];
            act[(w * 8 + 1) * 16 + lane] = c1[0];
            act[(w * 8 + 2) * 16 + lane] = c2[0];
            act[(w * 8 + 3) * 16 + lane] = c3[0];
            act[(w * 8 + 4) * 16 + lane] = c4[0];
            act[(w * 8 + 5) * 16 + lane] = c5[0];
            act[(w * 8 + 6) * 16 + lane] = c6[0];
            act[(w * 8 + 7) * 16 + lane] = c7[0];
        }
        asm volatile("s_waitcnt lgkmcnt(0)" ::: "memory");  // same-wave act done

        // ---- per-wave epilogue: lanes 0..31, unit u = 32w + lane ----
        if (lane < 32) {
            half2_t p01, p23;
            __builtin_memcpy(&p01, &gcu.x, 4);
            __builtin_memcpy(&p23, &gcu.y, 4);
            float4 g4v = ((const float4*)act)[u];              // a,i,f,o raw
            const float S = 0.0009765625f;                     // 2^-10
            float gA = g4v.x * S + (float)p01.x;
            float gB = g4v.y * S + (float)p01.y;
            float gC = g4v.z * S + (float)p23.x;
            float gD = g4v.w * S + (float)p23.y;
            float aa = fast_tanh(gA);
            float ii = fast_sigmoid(gB);
            float ff = fast_sigmoid(gC);
            float oo = fast_sigmoid(gD);
            s = aa * ii + s * ff;
            float h = fast_tanh(s) * oo;
            out[((size_t)t * BATCH + b) * HID + u] = h;
            unsigned p8 = cvt2_fp8<false>(h * 16.0f, h * 16.0f, 0u);
            hbufs[(t + 1) & 1][u] = (unsigned char)(p8 & 0xffu);
        }
        gcu = gnx;
        __syncthreads();   // hbuf slot complete before t+1 A-reads (1/step)
    }
}

extern "C" void kernel_launch(void* const* d_in, const int* in_sizes, int n_in,
                              void* d_out, int out_size, void* d_ws, size_t ws_size,
                              hipStream_t stream) {
    const float* X   = (const float*)d_in[0];
    const float* Wax = (const float*)d_in[1];
    const float* Wix = (const float*)d_in[2];
    const float* Wfx = (const float*)d_in[3];
    const float* Wox = (const float*)d_in[4];
    const float* Wah = (const float*)d_in[5];
    const float* Wih = (const float*)d_in[6];
    const float* Wfh = (const float*)d_in[7];
    const float* Woh = (const float*)d_in[8];
    const float* ba  = (const float*)d_in[9];
    const float* bi  = (const float*)d_in[10];
    const float* bf  = (const float*)d_in[11];
    const float* bo  = (const float*)d_in[12];

    _Float16* ws  = (_Float16*)d_ws;
    _Float16* Xh  = ws + XH_OFF;
    _Float16* Wxt = ws + WXT_OFF;
    _Float16* gxp = ws + GX_OFF;
    unsigned char* Wh8 = (unsigned char*)d_ws + WH8_BYTE_OFF;

    k_prep_x<<<dim3(GM * 256 / 4 / 256), dim3(256), 0, stream>>>(X, Xh);
    k_prep_w<<<dim3(1024), dim3(256), 0, stream>>>(Wax, Wix, Wfx, Wox, Wxt);
    k_prep_wfrag8<<<dim3(128), dim3(256), 0, stream>>>(Wah, Wih, Wfh, Woh, Wh8);
    k_gemm<<<dim3(GM / 128, G4 / 64), dim3(256), 0, stream>>>(
        Xh, Wxt, ba, bi, bf, bo, gxp);
    k_recur<<<dim3(BATCH), dim3(512), 0, stream>>>(Wh8, gxp, (float*)d_out);
}

// Round 23
// 843.507 us; speedup vs baseline: 1.0601x; 1.0061x over previous
//
#include <hip/hip_runtime.h>
#include <hip/hip_fp16.h>

// LSTM T=512 B=64 D=256 H=256, fp32 in/out.
//
// FINAL (lock-in of the best verified config, R16: 846.5us total, k_recur
// 733us, absmax 9.77e-4):
// Phase 0: X->f16; Wxt [4H][K] f16; Wh8 = Wh*64 quantized to fp8 e4m3,
//          MFMA B-fragment order, unit-major columns (c=4u+g).
// Phase 1: gx = X @ Wx + b via f16 MFMA GEMM -> ws f16 (unit-major store).
// Phase 2: recurrence, 1 CU/batch, 512 thr (8 waves, 2/SIMD). Wave owns
//          8 N-tiles = 64 fp8-B-longs, full Wh register-resident per CU
//          (zero per-step weight memory traffic). gates = h @ Wh via
//          mfma_f32_16x16x32_fp8_fp8, k-major interleave (8 indep MFMAs
//          per k-step). Central epilogue threads 0..255; hbuf double-buffer.
// Session ledger: 20831 (R1 scratch-spill) -> 3915 (split gx GEMM) ->
//  1717 (named-SSA reg residency) -> 1571 (gate-major) -> 955 (split-K hfma2)
//  -> 814 (fp8 MFMA k-major) -> 733 (8-wave 2/SIMD) = structural floor:
//  ~3.4k cyc/step = MFMA issue + compiler accvgpr moves (proven irremovable
//  at HIP level, R17-R19) + serial epilogue chain + barrier, x512 steps.

#define T_STEPS 512
#define BATCH   64
#define HID     256
#define G4      1024
#define GM      (T_STEPS * BATCH)     // 32768

typedef _Float16 half2_t __attribute__((ext_vector_type(2)));
typedef _Float16 f16x8   __attribute__((ext_vector_type(8)));
typedef float    f32x4   __attribute__((ext_vector_type(4)));

// ws layout
#define XH_OFF  0u          // f16[32768][256]
#define WXT_OFF 8388608u    // f16[1024][256]
#define GX_OFF  8912896u    // f16[32768][1024]
#define WH8_BYTE_OFF (8650752u * 2u)   // 256 KB fp8 frag-packed Wh

__device__ __forceinline__ float fast_sigmoid(float x) {
    return 1.0f / (1.0f + __expf(-x));
}
__device__ __forceinline__ float fast_tanh(float x) {
    return 2.0f / (1.0f + __expf(-2.0f * x)) - 1.0f;
}

// ---- fp8 e4m3fn encode (RN; flush |x|<2^-6 to 0; clamp to 448) ----
__device__ __forceinline__ unsigned char sw_e4m3(float x) {
    unsigned u = __float_as_uint(x);
    unsigned s = (u >> 24) & 0x80u;
    int e = (int)((u >> 23) & 0xffu) - 127;
    unsigned m = u & 0x7fffffu;
    if (e < -6) return (unsigned char)s;
    m += 0x00080000u;
    if (m & 0x800000u) { m = 0; e += 1; }
    int E = e + 7;
    if (E > 15 || (E == 15 && (m >> 20) > 6)) { E = 15; m = 6u << 20; }
    return (unsigned char)(s | ((unsigned)E << 3) | (m >> 20));
}
template <bool HI>
__device__ __forceinline__ unsigned cvt2_fp8(float a, float b, unsigned old) {
#if __has_builtin(__builtin_amdgcn_cvt_pk_fp8_f32)
    return (unsigned)__builtin_amdgcn_cvt_pk_fp8_f32(a, b, (int)old, HI);
#else
    unsigned lo16 = (unsigned)sw_e4m3(a) | ((unsigned)sw_e4m3(b) << 8);
    return HI ? ((old & 0xFFFFu) | (lo16 << 16))
              : ((old & 0xFFFF0000u) | lo16);
#endif
}

// ---------------- Phase 0a: X f32 -> f16 ----------------
__global__ __launch_bounds__(256) void k_prep_x(const float* __restrict__ X,
                                                _Float16* __restrict__ Xh) {
    const int i = blockIdx.x * 256 + threadIdx.x;
    float4 v = ((const float4*)X)[i];
    half2_t a; a.x = (_Float16)v.x; a.y = (_Float16)v.y;
    half2_t b; b.x = (_Float16)v.z; b.y = (_Float16)v.w;
    ((half2_t*)Xh)[2 * i]     = a;
    ((half2_t*)Xh)[2 * i + 1] = b;
}

// ---------------- Phase 0b: Wxt [4H][K] (gate-major cols) ----------------
__global__ __launch_bounds__(256) void k_prep_w(
    const float* __restrict__ Wax, const float* __restrict__ Wix,
    const float* __restrict__ Wfx, const float* __restrict__ Wox,
    _Float16* __restrict__ Wxt)
{
    const int id = blockIdx.x * 256 + threadIdx.x;
    const int k  = id >> 10;
    const int c  = id & 1023;
    const int g  = c >> 8;
    const int j  = c & 255;
    const float* src = (g == 0) ? Wax : (g == 1) ? Wix : (g == 2) ? Wfx : Wox;
    Wxt[c * 256 + k] = (_Float16)src[k * 256 + j];
}

// ---------------- Phase 0c: Wh8 fp8 fragments, unit-major cols -----------
__global__ __launch_bounds__(256) void k_prep_wfrag8(
    const float* __restrict__ Wah, const float* __restrict__ Wih,
    const float* __restrict__ Wfh, const float* __restrict__ Woh,
    unsigned char* __restrict__ Wh8)
{
    const int id  = blockIdx.x * 256 + threadIdx.x;   // [0, 32768)
    const int l   = id & 63;
    const int kt  = (id >> 6) & 7;
    const int ntG = id >> 9;
    const int c   = ntG * 16 + (l & 15);
    const int u   = c >> 2;
    const int g   = c & 3;
    const int k0  = kt * 32 + (l >> 4) * 8;
    const float* W = (g == 0) ? Wah : (g == 1) ? Wih : (g == 2) ? Wfh : Woh;
    float v[8];
#pragma unroll
    for (int e = 0; e < 8; ++e)
        v[e] = W[(size_t)(k0 + e) * 256 + u] * 64.0f;
    unsigned lo = cvt2_fp8<false>(v[0], v[1], 0u);
    lo = cvt2_fp8<true>(v[2], v[3], lo);
    unsigned hi = cvt2_fp8<false>(v[4], v[5], 0u);
    hi = cvt2_fp8<true>(v[6], v[7], hi);
    uint2 pk; pk.x = lo; pk.y = hi;
    *(uint2*)(Wh8 + ((size_t)(ntG * 8 + kt) * 64 + l) * 8) = pk;
}

// ---------------- Phase 1: gx = Xh @ Wxt^T + b (unit-major store) --------
__global__ __launch_bounds__(256) void k_gemm(const _Float16* __restrict__ Xh,
                                              const _Float16* __restrict__ Wxt,
                                              const float* __restrict__ ba,
                                              const float* __restrict__ bi,
                                              const float* __restrict__ bf_,
                                              const float* __restrict__ bo,
                                              _Float16* __restrict__ gx)
{
    const int lane = threadIdx.x & 63, wave = threadIdx.x >> 6;
    const int rowbase = blockIdx.x * 128 + wave * 32;
    const int colbase = blockIdx.y * 64;
    const int r15 = lane & 15, kg = lane >> 4;

    f32x4 acc[2][4] = {};
    const _Float16* ap0 = Xh  + (size_t)(rowbase + r15) * 256 + kg * 8;
    const _Float16* ap1 = ap0 + 16 * 256;
    const _Float16* bp  = Wxt + (size_t)(colbase + r15) * 256 + kg * 8;

#pragma unroll
    for (int ks = 0; ks < 8; ++ks) {
        f16x8 a0 = *(const f16x8*)(ap0 + ks * 32);
        f16x8 a1 = *(const f16x8*)(ap1 + ks * 32);
        f16x8 b0 = *(const f16x8*)(bp  + ks * 32);
        f16x8 b1 = *(const f16x8*)(bp  + 16 * 256 + ks * 32);
        f16x8 b2 = *(const f16x8*)(bp  + 32 * 256 + ks * 32);
        f16x8 b3 = *(const f16x8*)(bp  + 48 * 256 + ks * 32);
        acc[0][0] = __builtin_amdgcn_mfma_f32_16x16x32_f16(a0, b0, acc[0][0], 0, 0, 0);
        acc[0][1] = __builtin_amdgcn_mfma_f32_16x16x32_f16(a0, b1, acc[0][1], 0, 0, 0);
        acc[0][2] = __builtin_amdgcn_mfma_f32_16x16x32_f16(a0, b2, acc[0][2], 0, 0, 0);
        acc[0][3] = __builtin_amdgcn_mfma_f32_16x16x32_f16(a0, b3, acc[0][3], 0, 0, 0);
        acc[1][0] = __builtin_amdgcn_mfma_f32_16x16x32_f16(a1, b0, acc[1][0], 0, 0, 0);
        acc[1][1] = __builtin_amdgcn_mfma_f32_16x16x32_f16(a1, b1, acc[1][1], 0, 0, 0);
        acc[1][2] = __builtin_amdgcn_mfma_f32_16x16x32_f16(a1, b2, acc[1][2], 0, 0, 0);
        acc[1][3] = __builtin_amdgcn_mfma_f32_16x16x32_f16(a1, b3, acc[1][3], 0, 0, 0);
    }
    float bias_n[4];
#pragma unroll
    for (int nt = 0; nt < 4; ++nt) {
        int col = colbase + nt * 16 + r15;
        bias_n[nt] = (col < 256) ? ba[col]
                   : (col < 512) ? bi[col - 256]
                   : (col < 768) ? bf_[col - 512]
                                 : bo[col - 768];
    }
    // unit-major permuted store: col (= g*256+j) -> 4*j + g
#pragma unroll
    for (int mt = 0; mt < 2; ++mt)
#pragma unroll
        for (int nt = 0; nt < 4; ++nt)
#pragma unroll
            for (int r = 0; r < 4; ++r) {
                int row = rowbase + mt * 16 + kg * 4 + r;
                int col = colbase + nt * 16 + r15;
                int g   = col >> 8, j = col & 255;
                gx[(size_t)row * G4 + 4 * j + g] =
                    (_Float16)(acc[mt][nt][r] + bias_n[nt]);
            }
}

// ---------------- Phase 2: fp8 MFMA recurrence (8 waves, 2/SIMD) ---------

#define M8(a, bfr, acc) \
    __builtin_amdgcn_mfma_f32_16x16x32_fp8_fp8((a), (bfr), (acc), 0, 0, 0)
#define WB(n, k) (*(const long*)(Wp + ((size_t)((n) * 8 + (k)) * 64) * 8))

#define DB(n)                                                                  \
    long b##n##_0 = WB(n,0), b##n##_1 = WB(n,1), b##n##_2 = WB(n,2),           \
         b##n##_3 = WB(n,3), b##n##_4 = WB(n,4), b##n##_5 = WB(n,5),           \
         b##n##_6 = WB(n,6), b##n##_7 = WB(n,7);

// 8 independent MFMAs per k-step (one per owned tile)
#define KSTEP(k)                                                               \
    c0 = M8(a##k, b0_##k, c0);  c1 = M8(a##k, b1_##k, c1);                     \
    c2 = M8(a##k, b2_##k, c2);  c3 = M8(a##k, b3_##k, c3);                     \
    c4 = M8(a##k, b4_##k, c4);  c5 = M8(a##k, b5_##k, c5);                     \
    c6 = M8(a##k, b6_##k, c6);  c7 = M8(a##k, b7_##k, c7);

__global__ void __launch_bounds__(512, 1)
__attribute__((amdgpu_waves_per_eu(2, 2)))
k_recur(const unsigned char* __restrict__ Wh8, const _Float16* __restrict__ gx,
        float* __restrict__ out)
{
    const int b    = blockIdx.x;
    const int tid  = threadIdx.x;      // 0..511
    const int lane = tid & 63;
    const int w    = tid >> 6;         // wave 0..7: ntiles [8w, 8w+8)

    __shared__ __align__(16) float act[1024];          // 4 KB
    __shared__ __align__(8)  unsigned char hbufs[2][256];

    const unsigned char* Wp = Wh8 + ((size_t)(w * 8) * 8 * 64) * 8 + lane * 8;

    // ---- 64 register-resident fp8 B-fragment longs ----
    DB(0) DB(1) DB(2) DB(3) DB(4) DB(5) DB(6) DB(7)

    if (tid < 256) hbufs[0][tid] = 0;  // h0 = 0
    float s = 0.0f;
    uint2 gcu; gcu.x = 0u; gcu.y = 0u;
    if (tid < 256)
        gcu = *(const uint2*)(gx + (size_t)b * G4 + 4 * tid);  // a,i,f,o packed
    __syncthreads();

#pragma unroll 1
    for (int t = 0; t < T_STEPS; ++t) {
        // prefetch next-step gx: ONE 8B load (unit-major layout)
        uint2 gnx; gnx.x = 0u; gnx.y = 0u;
        if (tid < 256 && t + 1 < T_STEPS) {
            gnx = *(const uint2*)(gx + ((size_t)(t + 1) * BATCH + b) * G4 + 4 * tid);
        }

        // ---- A-fragments: fp8 h broadcast ----
        const unsigned char* hb = &hbufs[t & 1][0] + ((lane >> 4) * 8);
        long a0 = *(const long*)(hb + 0);
        long a1 = *(const long*)(hb + 32);
        long a2 = *(const long*)(hb + 64);
        long a3 = *(const long*)(hb + 96);
        long a4 = *(const long*)(hb + 128);
        long a5 = *(const long*)(hb + 160);
        long a6 = *(const long*)(hb + 192);
        long a7 = *(const long*)(hb + 224);

        f32x4 c0 = {0,0,0,0}, c1 = {0,0,0,0}, c2 = {0,0,0,0}, c3 = {0,0,0,0};
        f32x4 c4 = {0,0,0,0}, c5 = {0,0,0,0}, c6 = {0,0,0,0}, c7 = {0,0,0,0};

        KSTEP(0) KSTEP(1) KSTEP(2) KSTEP(3)
        KSTEP(4) KSTEP(5) KSTEP(6) KSTEP(7)

        // store row 0 of each owned C tile (lanes 0..15); global tile = 8w+n
        if (lane < 16) {
            act[(w * 8 + 0) * 16 + lane] = c0[0];
            act[(w * 8 + 1) * 16 + lane] = c1[0];
            act[(w * 8 + 2) * 16 + lane] = c2[0];
            act[(w * 8 + 3) * 16 + lane] = c3[0];
            act[(w * 8 + 4) * 16 + lane] = c4[0];
            act[(w * 8 + 5) * 16 + lane] = c5[0];
            act[(w * 8 + 6) * 16 + lane] = c6[0];
            act[(w * 8 + 7) * 16 + lane] = c7[0];
        }
        __syncthreads();   // act complete (cross-wave) + hbuf reads done

        // ---- epilogue: threads 0..255, unit u = tid ----
        if (tid < 256) {
            half2_t p01, p23;
            __builtin_memcpy(&p01, &gcu.x, 4);
            __builtin_memcpy(&p23, &gcu.y, 4);
            float4 g4v = ((const float4*)act)[tid];            // a,i,f,o raw
            const float S = 0.0009765625f;                     // 2^-10
            float gA = g4v.x * S + (float)p01.x;
            float gB = g4v.y * S + (float)p01.y;
            float gC = g4v.z * S + (float)p23.x;
            float gD = g4v.w * S + (float)p23.y;
            float aa = fast_tanh(gA);
            float ii = fast_sigmoid(gB);
            float ff = fast_sigmoid(gC);
            float oo = fast_sigmoid(gD);
            s = aa * ii + s * ff;
            float h = fast_tanh(s) * oo;
            out[((size_t)t * BATCH + b) * HID + tid] = h;
            unsigned p8 = cvt2_fp8<false>(h * 16.0f, h * 16.0f, 0u);
            hbufs[(t + 1) & 1][tid] = (unsigned char)(p8 & 0xffu);
        }
        gcu = gnx;
        __syncthreads();   // next slot complete before t+1 A-reads
    }
}

extern "C" void kernel_launch(void* const* d_in, const int* in_sizes, int n_in,
                              void* d_out, int out_size, void* d_ws, size_t ws_size,
                              hipStream_t stream) {
    const float* X   = (const float*)d_in[0];
    const float* Wax = (const float*)d_in[1];
    const float* Wix = (const float*)d_in[2];
    const float* Wfx = (const float*)d_in[3];
    const float* Wox = (const float*)d_in[4];
    const float* Wah = (const float*)d_in[5];
    const float* Wih = (const float*)d_in[6];
    const float* Wfh = (const float*)d_in[7];
    const float* Woh = (const float*)d_in[8];
    const float* ba  = (const float*)d_in[9];
    const float* bi  = (const float*)d_in[10];
    const float* bf  = (const float*)d_in[11];
    const float* bo  = (const float*)d_in[12];

    _Float16* ws  = (_Float16*)d_ws;
    _Float16* Xh  = ws + XH_OFF;
    _Float16* Wxt = ws + WXT_OFF;
    _Float16* gxp = ws + GX_OFF;
    unsigned char* Wh8 = (unsigned char*)d_ws + WH8_BYTE_OFF;

    k_prep_x<<<dim3(GM * 256 / 4 / 256), dim3(256), 0, stream>>>(X, Xh);
    k_prep_w<<<dim3(1024), dim3(256), 0, stream>>>(Wax, Wix, Wfx, Wox, Wxt);
    k_prep_wfrag8<<<dim3(128), dim3(256), 0, stream>>>(Wah, Wih, Wfh, Woh, Wh8);
    k_gemm<<<dim3(GM / 128, G4 / 64), dim3(256), 0, stream>>>(
        Xh, Wxt, ba, bi, bf, bo, gxp);
    k_recur<<<dim3(BATCH), dim3(512), 0, stream>>>(Wh8, gxp, (float*)d_out);
}